// Round 6
// baseline (796.842 us; speedup 1.0000x reference)
//
#include <hip/hip_runtime.h>
#include <hip/hip_bf16.h>

typedef unsigned short u16;
typedef unsigned int u32;
typedef __attribute__((ext_vector_type(8))) short bf16x8;
typedef __attribute__((ext_vector_type(8))) unsigned short u16x8;
typedef __attribute__((ext_vector_type(4))) unsigned short u16x4;
typedef __attribute__((ext_vector_type(4))) float f32x4;

#define DEVI __device__ __forceinline__

static constexpr int Bn = 8, Tn = 1024, Fn = 1024, Hn = 16, DKn = 64;
static constexpr int Mtot = Bn * Tn;  // 8192

DEVI u16 f2bf(float x) {
  unsigned u = __builtin_bit_cast(unsigned, x);
  u += 0x7fffu + ((u >> 16) & 1u);
  return (u16)(u >> 16);
}

DEVI u32 cvt_pk_bf16(float lo, float hi) {
  u32 r;
  asm("v_cvt_pk_bf16_f32 %0, %1, %2" : "=v"(r) : "v"(lo), "v"(hi));
  return r;
}

DEVI f32x4 mfma16(bf16x8 a, bf16x8 b, f32x4 c) {
  return __builtin_amdgcn_mfma_f32_16x16x32_bf16(a, b, c, 0, 0, 0);
}

typedef const __attribute__((address_space(1))) void GAS;
typedef __attribute__((address_space(3))) void LAS;
#define GLL16(gp, lp) __builtin_amdgcn_global_load_lds((GAS*)(gp), (LAS*)(lp), 16, 0, 0)

// ---------------- fp32 -> bf16 conversion (merged launches) ----------------
DEVI void cvt_chunk(const float* __restrict__ in, u16* __restrict__ out, int i) {
  const float4* p = reinterpret_cast<const float4*>(in + i);
  float4 a = p[0], b = p[1];
  float v[8] = {a.x, a.y, a.z, a.w, b.x, b.y, b.z, b.w};
  u16x8 r;
#pragma unroll
  for (int j = 0; j < 8; j++) r[j] = f2bf(v[j]);
  *reinterpret_cast<u16x8*>(out + i) = r;
}

__global__ __launch_bounds__(256) void cvt3(const float* __restrict__ a, const float* __restrict__ b,
                                            const float* __restrict__ c, u16* __restrict__ oa,
                                            u16* __restrict__ ob, u16* __restrict__ oc) {
  const int id = blockIdx.x * 256 + threadIdx.x;
  const int seg = id >> 20;
  const int off = (id & 1048575) * 8;
  const float* s = seg == 0 ? a : (seg == 1 ? b : c);
  u16* d = seg == 0 ? oa : (seg == 1 ? ob : oc);
  cvt_chunk(s, d, off);
}

__global__ __launch_bounds__(256) void cvt4(const float* __restrict__ a, const float* __restrict__ b,
                                            const float* __restrict__ c, const float* __restrict__ e,
                                            u16* __restrict__ oa, u16* __restrict__ ob,
                                            u16* __restrict__ oc, u16* __restrict__ oe) {
  const int id = blockIdx.x * 256 + threadIdx.x;
  const int seg = id >> 17;
  const int off = (id & 131071) * 8;
  const float* s = seg == 0 ? a : (seg == 1 ? b : (seg == 2 ? c : e));
  u16* d = seg == 0 ? oa : (seg == 1 ? ob : (seg == 2 ? oc : oe));
  cvt_chunk(s, d, off);
}

// ---------------- fused Q/K/V projection GEMM ----------------
// grid (256, 3): blockIdx.y = projection p (0=Q,1=K,2=V). BM=256 BN=128 BK=32,
// 512 thr = 8 waves (4Mx2N, 64x64/wave). LDS 48KB dbuf -> 2 blocks/CU co-resident
// (VGPR-capped at 128 via launch_bounds) so vmcnt/barrier stalls of one block
// overlap the other's compute. BK=32 => 64B rows: b128 frag reads spread evenly
// over bank groups ((4*lr+g) mod 8), so NO swizzle needed; staging fully linear.
// Counted vmcnt(3): next tile's 3 loads stay in flight across the barrier.
__global__ __launch_bounds__(512, 4) void qkv_gemm(
    const u16* __restrict__ Xq, const u16* __restrict__ Xk, const u16* __restrict__ Xv,
    const u16* __restrict__ Wq, const u16* __restrict__ Wk, const u16* __restrict__ Wv,
    const float* __restrict__ bq, const float* __restrict__ bk, const float* __restrict__ bv,
    u16* __restrict__ Qo, u16* __restrict__ Ko, u16* __restrict__ Vo, float SC) {
  constexpr int Kd = 1024;
  __shared__ u16 sA[2][256 * 32];
  __shared__ u16 sB[2][128 * 32];
  const int tid = threadIdx.x;
  const int l = tid & 63, w = tid >> 6;
  const int wm = w >> 1, wn = w & 1;
  const int lr = l & 15, g = l >> 4;
  const int p = blockIdx.y;
  const u16* A = p == 0 ? Xq : (p == 1 ? Xk : Xv);
  const u16* Bw = p == 0 ? Wq : (p == 1 ? Wk : Wv);
  const float* bias = p == 0 ? bq : (p == 1 ? bk : bv);
  u16* Obf = p == 0 ? Qo : (p == 1 ? Ko : Vo);
  const float oscale = p == 0 ? SC : 1.0f;
  // XCD swizzle within each projection layer
  const int bid = blockIdx.x;
  const int wg = (bid & 7) * 32 + (bid >> 3);
  const int m0 = (wg >> 3) * 256, n0 = (wg & 7) * 128;

  f32x4 acc[4][4];
#pragma unroll
  for (int i = 0; i < 4; i++)
#pragma unroll
    for (int j = 0; j < 4; j++) acc[i][j] = f32x4{0.f, 0.f, 0.f, 0.f};

  // linear staging: chunk c (16B) -> row c>>2, colchunk c&3
  int aoff[2];
#pragma unroll
  for (int i = 0; i < 2; i++) {
    const int c = i * 512 + tid;
    aoff[i] = (c >> 2) * Kd + (c & 3) * 8;
  }
  const int boff = (tid >> 2) * Kd + (tid & 3) * 8;
  const u16* Abase = A + (size_t)m0 * Kd;
  const u16* Bbase = Bw + (size_t)n0 * Kd;

  auto stage = [&](int buf, int kt) {
#pragma unroll
    for (int i = 0; i < 2; i++)
      GLL16(Abase + kt * 32 + aoff[i], (char*)&sA[buf][0] + (i * 512 + w * 64) * 16);
    GLL16(Bbase + kt * 32 + boff, (char*)&sB[buf][0] + (w * 64) * 16);
  };

  stage(0, 0);
  for (int t = 0; t < 32; ++t) {
    const int cur = t & 1;
    if (t < 31) {
      stage(cur ^ 1, t + 1);
      asm volatile("s_waitcnt vmcnt(3)" ::: "memory");
    } else {
      asm volatile("s_waitcnt vmcnt(0)" ::: "memory");
    }
    asm volatile("s_barrier" ::: "memory");
    bf16x8 af[4], bfr[4];
#pragma unroll
    for (int mi = 0; mi < 4; mi++)
      af[mi] = *reinterpret_cast<const bf16x8*>(
          (const char*)&sA[cur][0] + (wm * 64 + mi * 16 + lr) * 64 + g * 16);
#pragma unroll
    for (int ni = 0; ni < 4; ni++)
      bfr[ni] = *reinterpret_cast<const bf16x8*>(
          (const char*)&sB[cur][0] + (wn * 64 + ni * 16 + lr) * 64 + g * 16);
    __builtin_amdgcn_s_setprio(1);
    if (p == 2) {  // wave-uniform branch: V unswapped (rows=m)
#pragma unroll
      for (int mi = 0; mi < 4; mi++)
#pragma unroll
        for (int ni = 0; ni < 4; ni++) acc[mi][ni] = mfma16(af[mi], bfr[ni], acc[mi][ni]);
    } else {  // Q/K swapped (rows=n) -> vectorized (B,H,T,DK) stores
#pragma unroll
      for (int mi = 0; mi < 4; mi++)
#pragma unroll
        for (int ni = 0; ni < 4; ni++) acc[ni][mi] = mfma16(bfr[ni], af[mi], acc[ni][mi]);
    }
    __builtin_amdgcn_s_setprio(0);
    asm volatile("s_barrier" ::: "memory");
  }

  if (p == 2) {
    // V^T (B,H,DK,T): rows=m via (g,j) -> u16x4 along t
#pragma unroll
    for (int ni = 0; ni < 4; ni++) {
      const int n = n0 + wn * 64 + ni * 16 + lr;
      const float bvv = bias[n];
      const int h = n >> 6, dk = n & 63;
#pragma unroll
      for (int mi = 0; mi < 4; mi++) {
        const int mb = m0 + wm * 64 + mi * 16 + g * 4;
        u16x4 pk;
#pragma unroll
        for (int j = 0; j < 4; j++) pk[j] = f2bf(acc[mi][ni][j] + bvv);
        const int b = mb >> 10, tt = mb & 1023;
        size_t idx = (((size_t)b * 16 + h) * 64 + dk) * 1024 + tt;
        *reinterpret_cast<u16x4*>(Obf + idx) = pk;
      }
    }
  } else {
    // (B,H,T,DK): rows=n via (g,j) -> 4 consecutive dk per lane
#pragma unroll
    for (int ni = 0; ni < 4; ni++) {
      const int nb = n0 + wn * 64 + ni * 16 + g * 4;
      const float4 b4 = *reinterpret_cast<const float4*>(&bias[nb]);
#pragma unroll
      for (int mi = 0; mi < 4; mi++) {
        const int m = m0 + wm * 64 + mi * 16 + lr;
        const f32x4 a = acc[ni][mi];
        const int b = m >> 10, tt = m & 1023;
        const int h = nb >> 6, dk0 = nb & 63;
        u16x4 pk;
        pk[0] = f2bf((a[0] + b4.x) * oscale);
        pk[1] = f2bf((a[1] + b4.y) * oscale);
        pk[2] = f2bf((a[2] + b4.z) * oscale);
        pk[3] = f2bf((a[3] + b4.w) * oscale);
        *reinterpret_cast<u16x4*>(&Obf[((((size_t)b * 16 + h) * 1024 + tt) * 64) + dk0]) = pk;
      }
    }
  }
}

// ---------------- out-projection GEMM (R5 structure, fp32 out) ----------------
__global__ __launch_bounds__(512, 1) void gemm_out(const u16* __restrict__ A,
                                                   const u16* __restrict__ Bw,
                                                   const float* __restrict__ bias,
                                                   const float* __restrict__ mask,
                                                   float* __restrict__ Of) {
  constexpr int Kd = 1024;
  __shared__ u16 sA[2][256 * 64];
  __shared__ u16 sB[2][128 * 64];
  const int tid = threadIdx.x;
  const int l = tid & 63, w = tid >> 6;
  const int wm = w >> 1, wn = w & 1;
  const int lr = l & 15, g = l >> 4;
  const int bid = blockIdx.x;
  const int wg = (bid & 7) * 32 + (bid >> 3);
  const int m0 = (wg >> 3) * 256, n0 = (wg & 7) * 128;

  f32x4 acc[4][4];
#pragma unroll
  for (int i = 0; i < 4; i++)
#pragma unroll
    for (int j = 0; j < 4; j++) acc[i][j] = f32x4{0.f, 0.f, 0.f, 0.f};

  int aoff[4], boff[2];
#pragma unroll
  for (int i = 0; i < 4; i++) {
    const int c = i * 512 + tid;
    const int r = c >> 3, cc = (c & 7) ^ (r & 7);
    aoff[i] = r * Kd + cc * 8;
  }
#pragma unroll
  for (int i = 0; i < 2; i++) {
    const int c = i * 512 + tid;
    const int r = c >> 3, cc = (c & 7) ^ (r & 7);
    boff[i] = r * Kd + cc * 8;
  }
  const u16* Abase = A + (size_t)m0 * Kd;
  const u16* Bbase = Bw + (size_t)n0 * Kd;

  auto stage = [&](int buf, int kt) {
#pragma unroll
    for (int i = 0; i < 4; i++)
      GLL16(Abase + kt * 64 + aoff[i], (char*)&sA[buf][0] + (i * 512 + w * 64) * 16);
#pragma unroll
    for (int i = 0; i < 2; i++)
      GLL16(Bbase + kt * 64 + boff[i], (char*)&sB[buf][0] + (i * 512 + w * 64) * 16);
  };

  stage(0, 0);
  for (int t = 0; t < 16; ++t) {
    const int cur = t & 1;
    if (t < 15) {
      stage(cur ^ 1, t + 1);
      asm volatile("s_waitcnt vmcnt(6)" ::: "memory");
    } else {
      asm volatile("s_waitcnt vmcnt(0)" ::: "memory");
    }
    asm volatile("s_barrier" ::: "memory");
#pragma unroll
    for (int ks = 0; ks < 2; ks++) {
      bf16x8 af[4], bfr[4];
#pragma unroll
      for (int mi = 0; mi < 4; mi++) {
        const int row = wm * 64 + mi * 16 + lr;
        af[mi] = *reinterpret_cast<const bf16x8*>(
            (const char*)&sA[cur][0] + row * 128 + ((ks * 64 + g * 16) ^ ((row & 7) << 4)));
      }
#pragma unroll
      for (int ni = 0; ni < 4; ni++) {
        const int row = wn * 64 + ni * 16 + lr;
        bfr[ni] = *reinterpret_cast<const bf16x8*>(
            (const char*)&sB[cur][0] + row * 128 + ((ks * 64 + g * 16) ^ ((row & 7) << 4)));
      }
      __builtin_amdgcn_s_setprio(1);
#pragma unroll
      for (int mi = 0; mi < 4; mi++)
#pragma unroll
        for (int ni = 0; ni < 4; ni++) acc[ni][mi] = mfma16(bfr[ni], af[mi], acc[ni][mi]);
      __builtin_amdgcn_s_setprio(0);
    }
    asm volatile("s_barrier" ::: "memory");
  }

#pragma unroll
  for (int ni = 0; ni < 4; ni++) {
    const int nb = n0 + wn * 64 + ni * 16 + g * 4;
    const float4 b4 = *reinterpret_cast<const float4*>(&bias[nb]);
#pragma unroll
    for (int mi = 0; mi < 4; mi++) {
      const int m = m0 + wm * 64 + mi * 16 + lr;
      const f32x4 a = acc[ni][mi];
      const float mk = mask[m];
      float4 o;
      o.x = (a[0] + b4.x) * mk;
      o.y = (a[1] + b4.y) * mk;
      o.z = (a[2] + b4.z) * mk;
      o.w = (a[3] + b4.w) * mk;
      *reinterpret_cast<float4*>(&Of[(size_t)m * 1024 + nb]) = o;
    }
  }
}

// ---------------- flash attention: 4 waves x 16 q-rows, grid 2048 ----------------
// 5 blocks/CU (32KB LDS, VGPR capped) for VALU saturation. Per XCD: 16 bh of
// K/V = 4MB = L2. K dbuf + V single-buf (staged post-B2), P per-wave LDS,
// swapped-operand softmax, defer-max.
__global__ __launch_bounds__(256, 5) void flash_attn(const u16* __restrict__ Qb,
                                                     const u16* __restrict__ Kb,
                                                     const u16* __restrict__ Vt,
                                                     u16* __restrict__ ctx) {
  __shared__ u16 sK[2][64 * 64];
  __shared__ u16 sV[64 * 64];
  __shared__ u16 pbuf[4][16 * 64];
  const int tid = threadIdx.x, l = tid & 63, w = tid >> 6;
  const int lr = l & 15, g = l >> 4;
  const int wg = ((blockIdx.x & 7) << 8) + (blockIdx.x >> 3);  // bijective (2048%8==0)
  const int qt = wg & 15, bh = wg >> 4;
  const u16* Qh = Qb + (size_t)bh * (Tn * DKn);
  const u16* Kh = Kb + (size_t)bh * (Tn * DKn);
  const u16* Vh = Vt + (size_t)bh * (Tn * DKn);

  const int qrow = qt * 64 + w * 16 + lr;
  const bf16x8 aq0 = *reinterpret_cast<const bf16x8*>(Qh + (size_t)qrow * 64 + g * 8);
  const bf16x8 aq1 = *reinterpret_cast<const bf16x8*>(Qh + (size_t)qrow * 64 + 32 + g * 8);

  float mrow = -1e30f, lsum = 0.f;
  f32x4 of[4];
#pragma unroll
  for (int c = 0; c < 4; c++) of[c] = f32x4{0.f, 0.f, 0.f, 0.f};

  char* pb = (char*)&pbuf[w][0];
  const int sw = (lr & 7) << 4;
  int wadr[4];
#pragma unroll
  for (int c = 0; c < 4; c++) wadr[c] = lr * 128 + (((c * 16 + g * 4) * 2) ^ sw);
  const int radr0 = lr * 128 + ((g * 16) ^ sw);
  const int radr1 = lr * 128 + ((64 + g * 16) ^ sw);

  auto stageK = [&](int buf, int kv0) {
#pragma unroll
    for (int i = 0; i < 2; i++) {
      const int tt = i * 256 + tid;
      const int r = tt >> 3;
      const int c = (tt & 7) ^ (r & 7);
      GLL16((const char*)Kh + ((size_t)(kv0 + r) << 7) + (c << 4),
            (char*)&sK[buf][0] + i * 4096 + w * 1024);
    }
  };
  auto stageV = [&](int kv0) {
#pragma unroll
    for (int i = 0; i < 2; i++) {
      const int tt = i * 256 + tid;
      const int r = tt >> 3;
      const int c = (tt & 7) ^ (r & 7);
      GLL16((const char*)Vh + ((size_t)r << 11) + kv0 * 2 + (c << 4),
            (char*)&sV[0] + i * 4096 + w * 1024);
    }
  };

  stageK(0, 0);
  stageV(0);
  __syncthreads();
  int cur = 0;

  for (int t = 0; t < 16; t++) {
    if (t < 15) stageK(cur ^ 1, (t + 1) * 64);
    const char* kb = (const char*)&sK[cur][0];
    const char* vb = (const char*)&sV[0];

    // S^T = K . Q^T  (Q pre-scaled by 1/sqrt(dk)*log2e)
    f32x4 sf[4];
    __builtin_amdgcn_s_setprio(1);
#pragma unroll
    for (int c = 0; c < 4; c++) {
      const char* kr = kb + (c * 16 + lr) * 128;
      bf16x8 k0 = *reinterpret_cast<const bf16x8*>(kr + ((g * 16) ^ sw));
      bf16x8 k1 = *reinterpret_cast<const bf16x8*>(kr + ((64 + g * 16) ^ sw));
      f32x4 z = mfma16(k0, aq0, f32x4{0.f, 0.f, 0.f, 0.f});
      sf[c] = mfma16(k1, aq1, z);
    }
    __builtin_amdgcn_s_setprio(0);

    // defer-max online softmax
    f32x4 mx4 = sf[0];
#pragma unroll
    for (int c = 1; c < 4; c++)
#pragma unroll
      for (int j = 0; j < 4; j++) mx4[j] = fmaxf(mx4[j], sf[c][j]);
    const float pmax = fmaxf(fmaxf(mx4[0], mx4[1]), fmaxf(mx4[2], mx4[3]));
    if (__any(pmax > mrow + 8.0f)) {
      float mx = pmax;
      mx = fmaxf(mx, __shfl_xor(mx, 16));
      mx = fmaxf(mx, __shfl_xor(mx, 32));
      const float mn = fmaxf(mrow, mx);
      const float alpha = exp2f(mrow - mn);
      mrow = mn;
      lsum *= alpha;
#pragma unroll
      for (int c = 0; c < 4; c++)
#pragma unroll
        for (int j = 0; j < 4; j++) of[c][j] *= alpha;
    }
    float rs = 0.f;
#pragma unroll
    for (int c = 0; c < 4; c++)
#pragma unroll
      for (int j = 0; j < 4; j++) {
        float pp = exp2f(sf[c][j] - mrow);
        sf[c][j] = pp;
        rs += pp;
      }
    lsum += rs;

    // P -> per-wave LDS rows [q=lr][kv] (b64, swizzled), re-read as B-frags
#pragma unroll
    for (int c = 0; c < 4; c++) {
      uint2 pk;
      pk.x = cvt_pk_bf16(sf[c][0], sf[c][1]);
      pk.y = cvt_pk_bf16(sf[c][2], sf[c][3]);
      *reinterpret_cast<uint2*>(pb + wadr[c]) = pk;
    }
    const bf16x8 ap0 = *reinterpret_cast<const bf16x8*>(pb + radr0);
    const bf16x8 ap1 = *reinterpret_cast<const bf16x8*>(pb + radr1);

    __syncthreads();  // B1: sV(t) writes drained & visible

    // O^T += V^T . P^T
    __builtin_amdgcn_s_setprio(1);
#pragma unroll
    for (int d0 = 0; d0 < 4; d0++) {
      const char* vr = vb + (d0 * 16 + lr) * 128;
      bf16x8 v0 = *reinterpret_cast<const bf16x8*>(vr + ((g * 16) ^ sw));
      bf16x8 v1 = *reinterpret_cast<const bf16x8*>(vr + ((64 + g * 16) ^ sw));
      f32x4 z = mfma16(v0, ap0, of[d0]);
      of[d0] = mfma16(v1, ap1, z);
    }
    __builtin_amdgcn_s_setprio(0);

    __syncthreads();  // B2: all waves done reading sV(t)/sK[cur]
    if (t < 15) stageV((t + 1) * 64);
    cur ^= 1;
  }

  float ls = lsum;
  ls += __shfl_xor(ls, 16);
  ls += __shfl_xor(ls, 32);
  const float inv = 1.0f / ls;
  const int b = bh >> 4, h = bh & 15;
  const size_t base = ((size_t)b * 1024 + qrow) * 1024 + h * 64;
#pragma unroll
  for (int d0 = 0; d0 < 4; d0++) {
    uint2 pk;
    pk.x = cvt_pk_bf16(of[d0][0] * inv, of[d0][1] * inv);
    pk.y = cvt_pk_bf16(of[d0][2] * inv, of[d0][3] * inv);
    *reinterpret_cast<uint2*>(ctx + base + d0 * 16 + g * 4) = pk;
  }
}

// ---------------- launch ----------------
extern "C" void kernel_launch(void* const* d_in, const int* in_sizes, int n_in,
                              void* d_out, int out_size, void* d_ws, size_t ws_size,
                              hipStream_t stream) {
  const float* query = (const float*)d_in[0];
  const float* key = (const float*)d_in[1];
  const float* value = (const float*)d_in[2];
  const float* mask = (const float*)d_in[3];
  const float* Wq = (const float*)d_in[4];
  const float* bq = (const float*)d_in[5];
  const float* Wk = (const float*)d_in[6];
  const float* bk = (const float*)d_in[7];
  const float* Wv = (const float*)d_in[8];
  const float* bv = (const float*)d_in[9];
  const float* Wo = (const float*)d_in[10];
  const float* bo = (const float*)d_in[11];
  (void)in_sizes; (void)n_in; (void)out_size; (void)ws_size;

  u16* ws = (u16*)d_ws;
  const size_t MB8 = (size_t)8 << 20;  // 8M u16 = 16 MB
  u16* Xq = ws;                        // reused as ctx after Q-proj
  u16* Xk = ws + MB8;
  u16* Xv = ws + 2 * MB8;
  u16* Wqb = ws + 3 * MB8;
  u16* Wkb = Wqb + (1 << 20);
  u16* Wvb = Wkb + (1 << 20);
  u16* Wob = Wvb + (1 << 20);
  u16* Qb = Wob + (1 << 20);
  u16* Kb = Qb + MB8;
  u16* Vtb = Kb + MB8;
  u16* ctx = Xq;

  cvt3<<<12288, 256, 0, stream>>>(query, key, value, Xq, Xk, Xv);
  cvt4<<<2048, 256, 0, stream>>>(Wq, Wk, Wv, Wo, Wqb, Wkb, Wvb, Wob);

  const float SC = 0.125f * 1.44269504089f;  // 1/sqrt(DK) * log2(e)
  qkv_gemm<<<dim3(256, 3), 512, 0, stream>>>(Xq, Xk, Xv, Wqb, Wkb, Wvb, bq, bk, bv,
                                             Qb, Kb, Vtb, SC);

  flash_attn<<<Bn * Hn * (Tn / 64), 256, 0, stream>>>(Qb, Kb, Vtb, ctx);

  gemm_out<<<256, 512, 0, stream>>>(ctx, Wob, bo, mask, (float*)d_out);
}

// Round 7
// 204.141 us; speedup vs baseline: 3.9034x; 3.9034x over previous
//
#include <hip/hip_runtime.h>
#include <hip/hip_bf16.h>

typedef unsigned short u16;
typedef unsigned int u32;
typedef __attribute__((ext_vector_type(8))) short bf16x8;
typedef __attribute__((ext_vector_type(8))) unsigned short u16x8;
typedef __attribute__((ext_vector_type(4))) unsigned short u16x4;
typedef __attribute__((ext_vector_type(4))) float f32x4;

#define DEVI __device__ __forceinline__

static constexpr int Bn = 8, Tn = 1024, Fn = 1024, Hn = 16, DKn = 64;
static constexpr int Mtot = Bn * Tn;  // 8192

DEVI u16 f2bf(float x) {
  unsigned u = __builtin_bit_cast(unsigned, x);
  u += 0x7fffu + ((u >> 16) & 1u);
  return (u16)(u >> 16);
}

DEVI u32 cvt_pk_bf16(float lo, float hi) {
  u32 r;
  asm("v_cvt_pk_bf16_f32 %0, %1, %2" : "=v"(r) : "v"(lo), "v"(hi));
  return r;
}

DEVI f32x4 mfma16(bf16x8 a, bf16x8 b, f32x4 c) {
  return __builtin_amdgcn_mfma_f32_16x16x32_bf16(a, b, c, 0, 0, 0);
}

typedef const __attribute__((address_space(1))) void GAS;
typedef __attribute__((address_space(3))) void LAS;
#define GLL16(gp, lp) __builtin_amdgcn_global_load_lds((GAS*)(gp), (LAS*)(lp), 16, 0, 0)

// ---------------- fp32 -> bf16 conversion (merged launches) ----------------
DEVI void cvt_chunk(const float* __restrict__ in, u16* __restrict__ out, int i) {
  const float4* p = reinterpret_cast<const float4*>(in + i);
  float4 a = p[0], b = p[1];
  float v[8] = {a.x, a.y, a.z, a.w, b.x, b.y, b.z, b.w};
  u16x8 r;
#pragma unroll
  for (int j = 0; j < 8; j++) r[j] = f2bf(v[j]);
  *reinterpret_cast<u16x8*>(out + i) = r;
}

__global__ __launch_bounds__(256) void cvt3(const float* __restrict__ a, const float* __restrict__ b,
                                            const float* __restrict__ c, u16* __restrict__ oa,
                                            u16* __restrict__ ob, u16* __restrict__ oc) {
  const int id = blockIdx.x * 256 + threadIdx.x;
  const int seg = id >> 20;
  const int off = (id & 1048575) * 8;
  const float* s = seg == 0 ? a : (seg == 1 ? b : c);
  u16* d = seg == 0 ? oa : (seg == 1 ? ob : oc);
  cvt_chunk(s, d, off);
}

__global__ __launch_bounds__(256) void cvt4(const float* __restrict__ a, const float* __restrict__ b,
                                            const float* __restrict__ c, const float* __restrict__ e,
                                            u16* __restrict__ oa, u16* __restrict__ ob,
                                            u16* __restrict__ oc, u16* __restrict__ oe) {
  const int id = blockIdx.x * 256 + threadIdx.x;
  const int seg = id >> 17;
  const int off = (id & 131071) * 8;
  const float* s = seg == 0 ? a : (seg == 1 ? b : (seg == 2 ? c : e));
  u16* d = seg == 0 ? oa : (seg == 1 ? ob : (seg == 2 ? oc : oe));
  cvt_chunk(s, d, off);
}

// ---------------- GEMM  C[M,N] = (A[M,K] * W[N,K]^T + bias) * oscale ----------------
// R5-proven counted-vmcnt structure: BM=256 BN=128 BK=64, 512 thr = 8 waves
// (4Mx2N, 64x64/wave), LDS 96KB dbuf, launch_bounds(512,1) -- do NOT raise the
// 2nd arg: (512,4) capped VGPR at 64 and spilled acc to scratch (R6: 2.2GB HBM
// writes, 675us). Per K-tile: stage next (6 loads) -> vmcnt(6) -> barrier ->
// 2x{8 swizzled ds_read_b128 -> setprio(1) 16 MFMA setprio(0)} -> barrier.
// MODE 0: bf16 (B,H,T,DK) swapped-acc; MODE 1: bf16 (B,H,DK,T) unswapped;
// MODE 2: fp32 (M,N)*mask swapped-acc.
template <int MODE>
__global__ __launch_bounds__(512, 1) void gemm8(const u16* __restrict__ A,
                                                const u16* __restrict__ Bw,
                                                const float* __restrict__ bias,
                                                const float* __restrict__ mask,
                                                u16* __restrict__ Obf,
                                                float* __restrict__ Of,
                                                float oscale) {
  constexpr int Kd = 1024;
  __shared__ u16 sA[2][256 * 64];
  __shared__ u16 sB[2][128 * 64];
  const int tid = threadIdx.x;
  const int l = tid & 63, w = tid >> 6;
  const int wm = w >> 1, wn = w & 1;
  const int lr = l & 15, g = l >> 4;
  const int bid = blockIdx.x;
  const int wg = (bid & 7) * 32 + (bid >> 3);
  const int m0 = (wg >> 3) * 256, n0 = (wg & 7) * 128;

  f32x4 acc[4][4];
#pragma unroll
  for (int i = 0; i < 4; i++)
#pragma unroll
    for (int j = 0; j < 4; j++) acc[i][j] = f32x4{0.f, 0.f, 0.f, 0.f};

  int aoff[4], boff[2];
#pragma unroll
  for (int i = 0; i < 4; i++) {
    const int c = i * 512 + tid;
    const int r = c >> 3, cc = (c & 7) ^ (r & 7);
    aoff[i] = r * Kd + cc * 8;
  }
#pragma unroll
  for (int i = 0; i < 2; i++) {
    const int c = i * 512 + tid;
    const int r = c >> 3, cc = (c & 7) ^ (r & 7);
    boff[i] = r * Kd + cc * 8;
  }
  const u16* Abase = A + (size_t)m0 * Kd;
  const u16* Bbase = Bw + (size_t)n0 * Kd;

  auto stage = [&](int buf, int kt) {
#pragma unroll
    for (int i = 0; i < 4; i++)
      GLL16(Abase + kt * 64 + aoff[i], (char*)&sA[buf][0] + (i * 512 + w * 64) * 16);
#pragma unroll
    for (int i = 0; i < 2; i++)
      GLL16(Bbase + kt * 64 + boff[i], (char*)&sB[buf][0] + (i * 512 + w * 64) * 16);
  };

  stage(0, 0);
  for (int t = 0; t < 16; ++t) {
    const int cur = t & 1;
    if (t < 15) {
      stage(cur ^ 1, t + 1);
      asm volatile("s_waitcnt vmcnt(6)" ::: "memory");
    } else {
      asm volatile("s_waitcnt vmcnt(0)" ::: "memory");
    }
    asm volatile("s_barrier" ::: "memory");
#pragma unroll
    for (int ks = 0; ks < 2; ks++) {
      bf16x8 af[4], bfr[4];
#pragma unroll
      for (int mi = 0; mi < 4; mi++) {
        const int row = wm * 64 + mi * 16 + lr;
        af[mi] = *reinterpret_cast<const bf16x8*>(
            (const char*)&sA[cur][0] + row * 128 + ((ks * 64 + g * 16) ^ ((row & 7) << 4)));
      }
#pragma unroll
      for (int ni = 0; ni < 4; ni++) {
        const int row = wn * 64 + ni * 16 + lr;
        bfr[ni] = *reinterpret_cast<const bf16x8*>(
            (const char*)&sB[cur][0] + row * 128 + ((ks * 64 + g * 16) ^ ((row & 7) << 4)));
      }
      __builtin_amdgcn_s_setprio(1);
#pragma unroll
      for (int mi = 0; mi < 4; mi++)
#pragma unroll
        for (int ni = 0; ni < 4; ni++) {
          if constexpr (MODE == 1)
            acc[mi][ni] = mfma16(af[mi], bfr[ni], acc[mi][ni]);
          else
            acc[ni][mi] = mfma16(bfr[ni], af[mi], acc[ni][mi]);
        }
      __builtin_amdgcn_s_setprio(0);
    }
    asm volatile("s_barrier" ::: "memory");
  }

  if constexpr (MODE == 1) {
#pragma unroll
    for (int ni = 0; ni < 4; ni++) {
      const int n = n0 + wn * 64 + ni * 16 + lr;
      const float bv = bias[n];
      const int h = n >> 6, dk = n & 63;
#pragma unroll
      for (int mi = 0; mi < 4; mi++) {
        const int mb = m0 + wm * 64 + mi * 16 + g * 4;
        u16x4 pk;
#pragma unroll
        for (int j = 0; j < 4; j++) pk[j] = f2bf(acc[mi][ni][j] + bv);
        const int b = mb >> 10, tt = mb & 1023;
        size_t idx = (((size_t)b * 16 + h) * 64 + dk) * 1024 + tt;
        *reinterpret_cast<u16x4*>(Obf + idx) = pk;
      }
    }
  } else {
#pragma unroll
    for (int ni = 0; ni < 4; ni++) {
      const int nb = n0 + wn * 64 + ni * 16 + g * 4;
      const float4 b4 = *reinterpret_cast<const float4*>(&bias[nb]);
#pragma unroll
      for (int mi = 0; mi < 4; mi++) {
        const int m = m0 + wm * 64 + mi * 16 + lr;
        const f32x4 a = acc[ni][mi];
        if constexpr (MODE == 0) {
          const int b = m >> 10, tt = m & 1023;
          const int h = nb >> 6, dk0 = nb & 63;
          u16x4 pk;
          pk[0] = f2bf((a[0] + b4.x) * oscale);
          pk[1] = f2bf((a[1] + b4.y) * oscale);
          pk[2] = f2bf((a[2] + b4.z) * oscale);
          pk[3] = f2bf((a[3] + b4.w) * oscale);
          *reinterpret_cast<u16x4*>(&Obf[((((size_t)b * 16 + h) * 1024 + tt) * 64) + dk0]) = pk;
        } else {
          const float mk = mask[m];
          float4 o;
          o.x = (a[0] + b4.x) * mk;
          o.y = (a[1] + b4.y) * mk;
          o.z = (a[2] + b4.z) * mk;
          o.w = (a[3] + b4.w) * mk;
          *reinterpret_cast<float4*>(&Of[(size_t)m * 1024 + nb]) = o;
        }
      }
    }
  }
}

// ---------------- flash attention: 4 waves x 16 q-rows, grid 2048 ----------------
// 5 blocks/CU (32KB LDS x5 = 160KB). Per XCD: 16 bh of K/V = 4MB = L2.
// K dbuf + V single-buf (staged post-B2), P per-wave LDS, swapped-operand
// softmax, defer-max.
__global__ __launch_bounds__(256, 5) void flash_attn(const u16* __restrict__ Qb,
                                                     const u16* __restrict__ Kb,
                                                     const u16* __restrict__ Vt,
                                                     u16* __restrict__ ctx) {
  __shared__ u16 sK[2][64 * 64];
  __shared__ u16 sV[64 * 64];
  __shared__ u16 pbuf[4][16 * 64];
  const int tid = threadIdx.x, l = tid & 63, w = tid >> 6;
  const int lr = l & 15, g = l >> 4;
  const int wg = ((blockIdx.x & 7) << 8) + (blockIdx.x >> 3);  // bijective (2048%8==0)
  const int qt = wg & 15, bh = wg >> 4;
  const u16* Qh = Qb + (size_t)bh * (Tn * DKn);
  const u16* Kh = Kb + (size_t)bh * (Tn * DKn);
  const u16* Vh = Vt + (size_t)bh * (Tn * DKn);

  const int qrow = qt * 64 + w * 16 + lr;
  const bf16x8 aq0 = *reinterpret_cast<const bf16x8*>(Qh + (size_t)qrow * 64 + g * 8);
  const bf16x8 aq1 = *reinterpret_cast<const bf16x8*>(Qh + (size_t)qrow * 64 + 32 + g * 8);

  float mrow = -1e30f, lsum = 0.f;
  f32x4 of[4];
#pragma unroll
  for (int c = 0; c < 4; c++) of[c] = f32x4{0.f, 0.f, 0.f, 0.f};

  char* pb = (char*)&pbuf[w][0];
  const int sw = (lr & 7) << 4;
  int wadr[4];
#pragma unroll
  for (int c = 0; c < 4; c++) wadr[c] = lr * 128 + (((c * 16 + g * 4) * 2) ^ sw);
  const int radr0 = lr * 128 + ((g * 16) ^ sw);
  const int radr1 = lr * 128 + ((64 + g * 16) ^ sw);

  auto stageK = [&](int buf, int kv0) {
#pragma unroll
    for (int i = 0; i < 2; i++) {
      const int tt = i * 256 + tid;
      const int r = tt >> 3;
      const int c = (tt & 7) ^ (r & 7);
      GLL16((const char*)Kh + ((size_t)(kv0 + r) << 7) + (c << 4),
            (char*)&sK[buf][0] + i * 4096 + w * 1024);
    }
  };
  auto stageV = [&](int kv0) {
#pragma unroll
    for (int i = 0; i < 2; i++) {
      const int tt = i * 256 + tid;
      const int r = tt >> 3;
      const int c = (tt & 7) ^ (r & 7);
      GLL16((const char*)Vh + ((size_t)r << 11) + kv0 * 2 + (c << 4),
            (char*)&sV[0] + i * 4096 + w * 1024);
    }
  };

  stageK(0, 0);
  stageV(0);
  __syncthreads();
  int cur = 0;

  for (int t = 0; t < 16; t++) {
    if (t < 15) stageK(cur ^ 1, (t + 1) * 64);
    const char* kb = (const char*)&sK[cur][0];
    const char* vb = (const char*)&sV[0];

    // S^T = K . Q^T  (Q pre-scaled by 1/sqrt(dk)*log2e)
    f32x4 sf[4];
    __builtin_amdgcn_s_setprio(1);
#pragma unroll
    for (int c = 0; c < 4; c++) {
      const char* kr = kb + (c * 16 + lr) * 128;
      bf16x8 k0 = *reinterpret_cast<const bf16x8*>(kr + ((g * 16) ^ sw));
      bf16x8 k1 = *reinterpret_cast<const bf16x8*>(kr + ((64 + g * 16) ^ sw));
      f32x4 z = mfma16(k0, aq0, f32x4{0.f, 0.f, 0.f, 0.f});
      sf[c] = mfma16(k1, aq1, z);
    }
    __builtin_amdgcn_s_setprio(0);

    // defer-max online softmax
    f32x4 mx4 = sf[0];
#pragma unroll
    for (int c = 1; c < 4; c++)
#pragma unroll
      for (int j = 0; j < 4; j++) mx4[j] = fmaxf(mx4[j], sf[c][j]);
    const float pmax = fmaxf(fmaxf(mx4[0], mx4[1]), fmaxf(mx4[2], mx4[3]));
    if (__any(pmax > mrow + 8.0f)) {
      float mx = pmax;
      mx = fmaxf(mx, __shfl_xor(mx, 16));
      mx = fmaxf(mx, __shfl_xor(mx, 32));
      const float mn = fmaxf(mrow, mx);
      const float alpha = exp2f(mrow - mn);
      mrow = mn;
      lsum *= alpha;
#pragma unroll
      for (int c = 0; c < 4; c++)
#pragma unroll
        for (int j = 0; j < 4; j++) of[c][j] *= alpha;
    }
    float rs = 0.f;
#pragma unroll
    for (int c = 0; c < 4; c++)
#pragma unroll
      for (int j = 0; j < 4; j++) {
        float pp = exp2f(sf[c][j] - mrow);
        sf[c][j] = pp;
        rs += pp;
      }
    lsum += rs;

    // P -> per-wave LDS rows [q=lr][kv] (b64, swizzled), re-read as B-frags
#pragma unroll
    for (int c = 0; c < 4; c++) {
      uint2 pk;
      pk.x = cvt_pk_bf16(sf[c][0], sf[c][1]);
      pk.y = cvt_pk_bf16(sf[c][2], sf[c][3]);
      *reinterpret_cast<uint2*>(pb + wadr[c]) = pk;
    }
    const bf16x8 ap0 = *reinterpret_cast<const bf16x8*>(pb + radr0);
    const bf16x8 ap1 = *reinterpret_cast<const bf16x8*>(pb + radr1);

    __syncthreads();  // B1: sV(t) writes drained & visible

    // O^T += V^T . P^T
    __builtin_amdgcn_s_setprio(1);
#pragma unroll
    for (int d0 = 0; d0 < 4; d0++) {
      const char* vr = vb + (d0 * 16 + lr) * 128;
      bf16x8 v0 = *reinterpret_cast<const bf16x8*>(vr + ((g * 16) ^ sw));
      bf16x8 v1 = *reinterpret_cast<const bf16x8*>(vr + ((64 + g * 16) ^ sw));
      f32x4 z = mfma16(v0, ap0, of[d0]);
      of[d0] = mfma16(v1, ap1, z);
    }
    __builtin_amdgcn_s_setprio(0);

    __syncthreads();  // B2: all waves done reading sV(t)/sK[cur]
    if (t < 15) stageV((t + 1) * 64);
    cur ^= 1;
  }

  float ls = lsum;
  ls += __shfl_xor(ls, 16);
  ls += __shfl_xor(ls, 32);
  const float inv = 1.0f / ls;
  const int b = bh >> 4, h = bh & 15;
  const size_t base = ((size_t)b * 1024 + qrow) * 1024 + h * 64;
#pragma unroll
  for (int d0 = 0; d0 < 4; d0++) {
    uint2 pk;
    pk.x = cvt_pk_bf16(of[d0][0] * inv, of[d0][1] * inv);
    pk.y = cvt_pk_bf16(of[d0][2] * inv, of[d0][3] * inv);
    *reinterpret_cast<uint2*>(ctx + base + d0 * 16 + g * 4) = pk;
  }
}

// ---------------- launch ----------------
extern "C" void kernel_launch(void* const* d_in, const int* in_sizes, int n_in,
                              void* d_out, int out_size, void* d_ws, size_t ws_size,
                              hipStream_t stream) {
  const float* query = (const float*)d_in[0];
  const float* key = (const float*)d_in[1];
  const float* value = (const float*)d_in[2];
  const float* mask = (const float*)d_in[3];
  const float* Wq = (const float*)d_in[4];
  const float* bq = (const float*)d_in[5];
  const float* Wk = (const float*)d_in[6];
  const float* bk = (const float*)d_in[7];
  const float* Wv = (const float*)d_in[8];
  const float* bv = (const float*)d_in[9];
  const float* Wo = (const float*)d_in[10];
  const float* bo = (const float*)d_in[11];
  (void)in_sizes; (void)n_in; (void)out_size; (void)ws_size;

  u16* ws = (u16*)d_ws;
  const size_t MB8 = (size_t)8 << 20;  // 8M u16 = 16 MB
  u16* Xq = ws;                        // reused as ctx after Q-proj
  u16* Xk = ws + MB8;
  u16* Xv = ws + 2 * MB8;
  u16* Wqb = ws + 3 * MB8;
  u16* Wkb = Wqb + (1 << 20);
  u16* Wvb = Wkb + (1 << 20);
  u16* Wob = Wvb + (1 << 20);
  u16* Qb = Wob + (1 << 20);
  u16* Kb = Qb + MB8;
  u16* Vtb = Kb + MB8;
  u16* ctx = Xq;

  cvt3<<<12288, 256, 0, stream>>>(query, key, value, Xq, Xk, Xv);
  cvt4<<<2048, 256, 0, stream>>>(Wq, Wk, Wv, Wo, Wqb, Wkb, Wvb, Wob);

  const float SC = 0.125f * 1.44269504089f;  // 1/sqrt(DK) * log2(e)
  const int ng = (Mtot / 256) * (Fn / 128);  // 256 blocks
  gemm8<0><<<ng, 512, 0, stream>>>(Xq, Wqb, bq, nullptr, Qb, nullptr, SC);
  gemm8<0><<<ng, 512, 0, stream>>>(Xk, Wkb, bk, nullptr, Kb, nullptr, 1.0f);
  gemm8<1><<<ng, 512, 0, stream>>>(Xv, Wvb, bv, nullptr, Vtb, nullptr, 1.0f);

  flash_attn<<<Bn * Hn * (Tn / 64), 256, 0, stream>>>(Qb, Kb, Vtb, ctx);

  gemm8<2><<<256, 512, 0, stream>>>(ctx, Wob, bo, mask, nullptr, (float*)d_out, 1.0f);
}